// Round 7
// baseline (98.061 us; speedup 1.0000x reference)
//
#include <hip/hip_runtime.h>
#include <hip/hip_bf16.h>

typedef __attribute__((ext_vector_type(8))) short short8;   // 8 x bf16 (4 VGPR)
typedef __attribute__((ext_vector_type(4))) float f32x4;
typedef __attribute__((ext_vector_type(4))) int   i32x4;

#define KD 4096
#define ND 16384
#define MD 128

// round-to-nearest-even f32 -> bf16 bits
__device__ __forceinline__ ushort f2bf_rn(float f) {
    unsigned u = __float_as_uint(f);
    u += 0x7FFFu + ((u >> 16) & 1u);
    return (ushort)(u >> 16);
}

// exact for |v| <= 127: int -> f32 -> truncate to bf16 (small ints have zero low mantissa bits)
__device__ __forceinline__ ushort i2bf(int v) {
    return (ushort)(__float_as_uint((float)v) >> 16);
}

// Pack x[128][4096] f32 into bf16 MFMA A-fragment order (verified r1/r3):
// xp[kb][mt][lane][j] = x[16*mt + (lane&15)][32*kb + 8*(lane>>4) + j]   (1 MiB)
__global__ __launch_bounds__(256) void pack_x_kernel(const float* __restrict__ x,
                                                     ushort* __restrict__ xp) {
    int tid  = blockIdx.x * 256 + threadIdx.x;   // 0..65535
    int lane = tid & 63;
    int mt   = (tid >> 6) & 7;
    int kb   = tid >> 9;                          // 0..127
    int m = (mt << 4) + (lane & 15);
    int k = (kb << 5) + ((lane >> 4) << 3);
    const f32x4* src = reinterpret_cast<const f32x4*>(x + (size_t)m * KD + k);
    f32x4 a = src[0];
    f32x4 b = src[1];
    short8 v;
    v[0] = (short)f2bf_rn(a[0]); v[1] = (short)f2bf_rn(a[1]);
    v[2] = (short)f2bf_rn(a[2]); v[3] = (short)f2bf_rn(a[3]);
    v[4] = (short)f2bf_rn(b[0]); v[5] = (short)f2bf_rn(b[1]);
    v[6] = (short)f2bf_rn(b[2]); v[7] = (short)f2bf_rn(b[3]);
    *reinterpret_cast<short8*>(xp + (size_t)tid * 8) = v;
}

#define GLOAD_LDS16(g, l)                                                        \
    __builtin_amdgcn_global_load_lds((const __attribute__((address_space(1))) void*)(g), \
                                     (__attribute__((address_space(3))) void*)(l), 16, 0, 0)

// counted-vmcnt phase boundary (memory clobber = full optimizer fence)
#define WAITB(n) do {                                                            \
        asm volatile("s_waitcnt vmcnt(" #n ")" ::: "memory");                    \
        __builtin_amdgcn_s_barrier();                                            \
    } while (0)

// opaque LDS read: no memory clobber -> waitcnt legalizer inserts NO vmcnt
// before it; volatile -> ordered vs the WAITB asm. Data validity is enforced
// manually by lgkmcnt(0) + sched_barrier(0) before consumers (rule 18).
#define DSREAD(dst, addr)                                                        \
    asm volatile("ds_read_b128 %0, %1" : "=v"(dst) : "v"(addr))

__device__ __forceinline__ unsigned as3off(const char* p) {
    return (unsigned)(uintptr_t)(const __attribute__((address_space(3))) char*)p;
}

// Block: 64 output cols x 64 output rows (m-half) x full K=4096.
// Grid 512 = 256 n-groups x 2 m-halves; pair (nb, nb+256) shares W cols on same XCD.
// LDS: A 3x8KiB [0,24K) + W 3x16KiB [24K,72K) -> 2 blocks/CU.
// Depth-3 pipeline: phase t = { WAITB(6) [stage(t) landed, stage(t+1) in flight];
// STAGE(t+2); COMPUTE(t) }. Compute reads are opaque asm ds_read_b128 so the
// compiler cannot insert a hidden vmcnt(0) drain (r4's suspected failure).
__global__ __launch_bounds__(256, 2) void gemm_kernel(const int* __restrict__ wgt,
                                                      const ushort* __restrict__ xp,
                                                      const float* __restrict__ scales,
                                                      const float* __restrict__ bias,
                                                      float* __restrict__ out) {
    __shared__ __align__(16) char lds[73728];

    const int tid  = threadIdx.x;
    const int lane = tid & 63;
    const int w    = tid >> 6;          // wave 0..3 -> col group [16w,16w+16)
    const int nb   = blockIdx.x & 255;  // n-group
    const int h    = blockIdx.x >> 8;   // m-half
    const int n0   = nb << 6;
    const int cl   = lane & 15;
    const int cq   = lane >> 4;         // k-quarter 0..3

    // ---- staging sources (identical to r3/r4, verified) ----
    const char* asrc = (const char*)xp + (h << 12) + (w << 10) + (lane << 4);
    const int* wsrc0;
    const int* wsrc1;
    const int* wsrc2;
    const int* wsrc3;
    {
        int c0 = (w << 4) + 0  + cq;
        int c1 = (w << 4) + 4  + cq;
        int c2 = (w << 4) + 8  + cq;
        int c3 = (w << 4) + 12 + cq;
        wsrc0 = wgt + (size_t)(n0 + c0) * KD + ((cl ^ (c0 & 7)) << 2);
        wsrc1 = wgt + (size_t)(n0 + c1) * KD + ((cl ^ (c1 & 7)) << 2);
        wsrc2 = wgt + (size_t)(n0 + c2) * KD + ((cl ^ (c2 & 7)) << 2);
        wsrc3 = wgt + (size_t)(n0 + c3) * KD + ((cl ^ (c3 & 7)) << 2);
    }

    f32x4 acc[4];
#pragma unroll
    for (int i = 0; i < 4; ++i) acc[i] = (f32x4){0.f, 0.f, 0.f, 0.f};

    // LDS dest bases (wave-uniform; HW adds lane*16)
    char* dA = lds + (w << 10);                       // + b*8192 + j*4096
    char* dW = lds + 24576 + (w << 12);               // + b*16384 + _i*1024

#define STAGE(t, b) do {                                                        \
        const char* _as = asrc + (size_t)(t) * 16384;                           \
        GLOAD_LDS16(_as,        dA + (b) * 8192);                               \
        GLOAD_LDS16(_as + 8192, dA + (b) * 8192 + 4096);                        \
        const int _k0 = (t) * 64;                                               \
        GLOAD_LDS16(wsrc0 + _k0, dW + (b) * 16384);                             \
        GLOAD_LDS16(wsrc1 + _k0, dW + (b) * 16384 + 1024);                      \
        GLOAD_LDS16(wsrc2 + _k0, dW + (b) * 16384 + 2048);                      \
        GLOAD_LDS16(wsrc3 + _k0, dW + (b) * 16384 + 3072);                      \
    } while (0)

    // compute-side read offsets (AS3 32-bit, r3's verified layout)
    const unsigned rAoff = as3off(lds + (lane << 4));
    const unsigned rWoff = as3off(lds + 24576 + (((w << 4) + cl) << 8));
    const unsigned sw  = (unsigned)((cl & 7) << 4);
    const unsigned q32 = (unsigned)(cq << 5);
    const unsigned ib0 = q32 ^ sw;            // kbl=0
    const unsigned ib1 = (128u + q32) ^ sw;   // kbl=1

#define COMPUTE(b) do {                                                         \
        i32x4 _wl0, _wh0, _wl1, _wh1;                                           \
        short8 _a00, _a01, _a02, _a03, _a10, _a11, _a12, _a13;                  \
        const unsigned _wb = rWoff + (b) * 16384u;                              \
        DSREAD(_wl0, _wb + ib0); DSREAD(_wh0, _wb + (ib0 ^ 16u));               \
        DSREAD(_wl1, _wb + ib1); DSREAD(_wh1, _wb + (ib1 ^ 16u));               \
        const unsigned _ab = rAoff + (b) * 8192u;                               \
        DSREAD(_a00, _ab);         DSREAD(_a01, _ab + 1024u);                   \
        DSREAD(_a02, _ab + 2048u); DSREAD(_a03, _ab + 3072u);                   \
        DSREAD(_a10, _ab + 4096u); DSREAD(_a11, _ab + 5120u);                   \
        DSREAD(_a12, _ab + 6144u); DSREAD(_a13, _ab + 7168u);                   \
        asm volatile("s_waitcnt lgkmcnt(0)");                                   \
        __builtin_amdgcn_sched_barrier(0);                                      \
        short8 _bf0, _bf1;                                                      \
        _bf0[0] = (short)i2bf(_wl0[0]); _bf0[1] = (short)i2bf(_wl0[1]);         \
        _bf0[2] = (short)i2bf(_wl0[2]); _bf0[3] = (short)i2bf(_wl0[3]);         \
        _bf0[4] = (short)i2bf(_wh0[0]); _bf0[5] = (short)i2bf(_wh0[1]);         \
        _bf0[6] = (short)i2bf(_wh0[2]); _bf0[7] = (short)i2bf(_wh0[3]);         \
        _bf1[0] = (short)i2bf(_wl1[0]); _bf1[1] = (short)i2bf(_wl1[1]);         \
        _bf1[2] = (short)i2bf(_wl1[2]); _bf1[3] = (short)i2bf(_wl1[3]);         \
        _bf1[4] = (short)i2bf(_wh1[0]); _bf1[5] = (short)i2bf(_wh1[1]);         \
        _bf1[6] = (short)i2bf(_wh1[2]); _bf1[7] = (short)i2bf(_wh1[3]);         \
        acc[0] = __builtin_amdgcn_mfma_f32_16x16x32_bf16(_a00, _bf0, acc[0], 0, 0, 0); \
        acc[1] = __builtin_amdgcn_mfma_f32_16x16x32_bf16(_a01, _bf0, acc[1], 0, 0, 0); \
        acc[2] = __builtin_amdgcn_mfma_f32_16x16x32_bf16(_a02, _bf0, acc[2], 0, 0, 0); \
        acc[3] = __builtin_amdgcn_mfma_f32_16x16x32_bf16(_a03, _bf0, acc[3], 0, 0, 0); \
        acc[0] = __builtin_amdgcn_mfma_f32_16x16x32_bf16(_a10, _bf1, acc[0], 0, 0, 0); \
        acc[1] = __builtin_amdgcn_mfma_f32_16x16x32_bf16(_a11, _bf1, acc[1], 0, 0, 0); \
        acc[2] = __builtin_amdgcn_mfma_f32_16x16x32_bf16(_a12, _bf1, acc[2], 0, 0, 0); \
        acc[3] = __builtin_amdgcn_mfma_f32_16x16x32_bf16(_a13, _bf1, acc[3], 0, 0, 0); \
    } while (0)

    // ---- main loop: 64 chunks of K=64, buffer = chunk % 3 ----
    STAGE(0, 0);
    STAGE(1, 1);

#pragma unroll 1
    for (int i = 0; i < 20; ++i) {
        const int t = i * 3;
        WAITB(6); STAGE(t + 2, 2); COMPUTE(0);    // chunk t   (b0)
        WAITB(6); STAGE(t + 3, 0); COMPUTE(1);    // chunk t+1 (b1)
        WAITB(6); STAGE(t + 4, 1); COMPUTE(2);    // chunk t+2 (b2)
    }
    // chunks 60..63; staged so far: 0..61
    WAITB(6); STAGE(62, 2); COMPUTE(0);           // chunk 60
    WAITB(6); STAGE(63, 0); COMPUTE(1);           // chunk 61
    WAITB(6);                COMPUTE(2);          // chunk 62 (only stage63 outstanding)
    WAITB(0);                COMPUTE(0);          // chunk 63 (drained)

    // ---- epilogue: scale + bias, direct store (block owns its 64x64 tile) ----
    const int ncol = n0 + (w << 4) + cl;
    const float s  = scales[ncol] * (1.0f / 127.0f);
    const float bv = bias[ncol];
    const int rb = cq << 2;
#pragma unroll
    for (int m = 0; m < 4; ++m) {
#pragma unroll
        for (int r = 0; r < 4; ++r) {
            int mg = (h << 6) + (m << 4) + rb + r;
            out[(size_t)mg * ND + ncol] = acc[m][r] * s + bv;
        }
    }
#undef STAGE
#undef COMPUTE
}

extern "C" void kernel_launch(void* const* d_in, const int* in_sizes, int n_in,
                              void* d_out, int out_size, void* d_ws, size_t ws_size,
                              hipStream_t stream) {
    const float* x      = (const float*)d_in[0];
    const int*   wgt    = (const int*)d_in[1];     // int8 promoted to int32 by harness
    const float* scales = (const float*)d_in[2];
    const float* bias   = (const float*)d_in[3];
    float* out = (float*)d_out;
    ushort* xp = (ushort*)d_ws;                    // 1 MiB bf16 packed x

    pack_x_kernel<<<MD * KD / (8 * 256), 256, 0, stream>>>(x, xp);
    gemm_kernel<<<512, 256, 0, stream>>>(wgt, xp, scales, bias, out);
}

// Round 8
// 95.002 us; speedup vs baseline: 1.0322x; 1.0322x over previous
//
#include <hip/hip_runtime.h>
#include <hip/hip_bf16.h>

typedef __attribute__((ext_vector_type(8))) short short8;   // 8 x bf16 (4 VGPR)
typedef __attribute__((ext_vector_type(4))) float f32x4;
typedef __attribute__((ext_vector_type(4))) int   i32x4;

#define KD 4096
#define ND 16384
#define MD 128

// round-to-nearest-even f32 -> bf16 bits
__device__ __forceinline__ ushort f2bf_rn(float f) {
    unsigned u = __float_as_uint(f);
    u += 0x7FFFu + ((u >> 16) & 1u);
    return (ushort)(u >> 16);
}

// exact for |v| <= 127: int -> f32 -> truncate to bf16 (small ints have zero low mantissa bits)
__device__ __forceinline__ ushort i2bf(int v) {
    return (ushort)(__float_as_uint((float)v) >> 16);
}

// Pack x[128][4096] f32 into bf16 MFMA A-fragment order (verified r1/r3):
// xp[kb][mt][lane][j] = x[16*mt + (lane&15)][32*kb + 8*(lane>>4) + j]   (1 MiB)
__global__ __launch_bounds__(256) void pack_x_kernel(const float* __restrict__ x,
                                                     ushort* __restrict__ xp) {
    int tid  = blockIdx.x * 256 + threadIdx.x;   // 0..65535
    int lane = tid & 63;
    int mt   = (tid >> 6) & 7;
    int kb   = tid >> 9;                          // 0..127
    int m = (mt << 4) + (lane & 15);
    int k = (kb << 5) + ((lane >> 4) << 3);
    const f32x4* src = reinterpret_cast<const f32x4*>(x + (size_t)m * KD + k);
    f32x4 a = src[0];
    f32x4 b = src[1];
    short8 v;
    v[0] = (short)f2bf_rn(a[0]); v[1] = (short)f2bf_rn(a[1]);
    v[2] = (short)f2bf_rn(a[2]); v[3] = (short)f2bf_rn(a[3]);
    v[4] = (short)f2bf_rn(b[0]); v[5] = (short)f2bf_rn(b[1]);
    v[6] = (short)f2bf_rn(b[2]); v[7] = (short)f2bf_rn(b[3]);
    *reinterpret_cast<short8*>(xp + (size_t)tid * 8) = v;
}

#define GLOAD_LDS16(g, l)                                                        \
    __builtin_amdgcn_global_load_lds((const __attribute__((address_space(1))) void*)(g), \
                                     (__attribute__((address_space(3))) void*)(l), 16, 0, 0)

// Block: 64 output cols x 64 output rows (m-half) x full K=4096. 4 waves own 16 cols each.
// Grid 512 = 256 n-groups x 2 m-halves; pair (nb, nb+256) shares W cols on same XCD
// (L2 dedup, verified r3). K-chunk = 128. LDS = W only, dbuf 2x32KiB -> 2 blocks/CU.
// Verified 2-phase template: ALOAD(t) [A: global->reg, L1/L2-served, issued FIRST so
// vmcnt in-order retire keeps W in flight]; STAGE_W(t+1); COMPUTE(t); __syncthreads().
__global__ __launch_bounds__(256, 2) void gemm_kernel(const int* __restrict__ wgt,
                                                      const ushort* __restrict__ xp,
                                                      const float* __restrict__ scales,
                                                      const float* __restrict__ bias,
                                                      float* __restrict__ out) {
    __shared__ __align__(16) char lds[65536];   // W: 2 x 32 KiB; layout col(64) x 512B swizzled

    const int tid  = threadIdx.x;
    const int lane = tid & 63;
    const int w    = tid >> 6;          // wave 0..3 -> col group [16w,16w+16)
    const int nb   = blockIdx.x & 255;  // n-group
    const int h    = blockIdx.x >> 8;   // m-half
    const int n0   = nb << 6;
    const int cl   = lane & 15;
    const int cq   = lane >> 4;         // k-quarter 0..3

    // ---- A source: chunk t, q, kbl -> xp + t*32768 + kbl*8192 + h*4096 + q*1024 + lane*16
    const char* axbase = (const char*)xp + (h << 12) + (lane << 4);

    // ---- W staging sources: 8 issues/wave; issue i, lane l writes LDS linear
    // dest w*8192 + i*1024 + l*16 -> col c = 16w + 2i + (l>>5), inner = (l&31)*16.
    // Target layout inner(c,k) = (4k) ^ ((c&7)<<4)  =>  k = 4*(l&31) ^ ((c&7)<<2).
    const int l5  = lane >> 5;
    const int l31 = lane & 31;
    const int* wsrc[8];
#pragma unroll
    for (int i = 0; i < 8; ++i) {
        int c = (w << 4) + (i << 1) + l5;
        int koff = (l31 << 2) ^ ((c & 7) << 2);
        wsrc[i] = wgt + (size_t)(n0 + c) * KD + koff;
    }

    f32x4 acc[4];
#pragma unroll
    for (int i = 0; i < 4; ++i) acc[i] = (f32x4){0.f, 0.f, 0.f, 0.f};

    short8 afr[16];                     // [q][kbl] A fragments for current chunk

    // LDS dest base (wave-uniform; HW adds lane*16)
    char* dW = lds + (w << 13);         // + b*32768 + i*1024

#define STAGE(t, b) do {                                                        \
        char* _d = dW + (b) * 32768;                                            \
        _Pragma("unroll")                                                       \
        for (int _i = 0; _i < 8; ++_i)                                          \
            GLOAD_LDS16(wsrc[_i] + (t) * 128, _d + _i * 1024);                  \
    } while (0)

#define ALOAD(t) do {                                                           \
        const char* _ax = axbase + (size_t)(t) * 32768;                         \
        _Pragma("unroll")                                                       \
        for (int _q = 0; _q < 4; ++_q)                                          \
            _Pragma("unroll")                                                   \
            for (int _kb = 0; _kb < 4; ++_kb)                                   \
                afr[_q * 4 + _kb] = *reinterpret_cast<const short8*>(           \
                    _ax + _kb * 8192 + _q * 1024);                              \
    } while (0)

    // compute-side W read: col (16w+cl) at 512B stride; swizzled inner
    const char* rW = lds + (((w << 4) + cl) << 9);
    const unsigned sw  = (unsigned)((cl & 7) << 4);
    const unsigned q32 = (unsigned)(cq << 5);

#define COMPUTE(b) do {                                                         \
        const char* _wc = rW + (b) * 32768;                                     \
        _Pragma("unroll")                                                       \
        for (int _kb = 0; _kb < 4; ++_kb) {                                     \
            unsigned _off = (unsigned)((_kb << 7) + q32) ^ sw;                  \
            i32x4 _lo = *reinterpret_cast<const i32x4*>(_wc + _off);            \
            i32x4 _hi = *reinterpret_cast<const i32x4*>(_wc + (_off ^ 16u));    \
            short8 _bf;                                                         \
            _bf[0] = (short)i2bf(_lo[0]); _bf[1] = (short)i2bf(_lo[1]);         \
            _bf[2] = (short)i2bf(_lo[2]); _bf[3] = (short)i2bf(_lo[3]);         \
            _bf[4] = (short)i2bf(_hi[0]); _bf[5] = (short)i2bf(_hi[1]);         \
            _bf[6] = (short)i2bf(_hi[2]); _bf[7] = (short)i2bf(_hi[3]);         \
            acc[0] = __builtin_amdgcn_mfma_f32_16x16x32_bf16(afr[0 * 4 + _kb], _bf, acc[0], 0, 0, 0); \
            acc[1] = __builtin_amdgcn_mfma_f32_16x16x32_bf16(afr[1 * 4 + _kb], _bf, acc[1], 0, 0, 0); \
            acc[2] = __builtin_amdgcn_mfma_f32_16x16x32_bf16(afr[2 * 4 + _kb], _bf, acc[2], 0, 0, 0); \
            acc[3] = __builtin_amdgcn_mfma_f32_16x16x32_bf16(afr[3 * 4 + _kb], _bf, acc[3], 0, 0, 0); \
        }                                                                       \
    } while (0)

    // ---- main loop: 32 chunks of K=128, verified 2-phase template ----
    STAGE(0, 0);
    __syncthreads();
#pragma unroll 1
    for (int t = 0; t < 31; ++t) {
        ALOAD(t);                              // A loads first (oldest in vmcnt queue)
        __builtin_amdgcn_sched_barrier(0);     // pin: A issue stays before W issue
        STAGE(t + 1, (t + 1) & 1);
        COMPUTE(t & 1);
        __syncthreads();                       // drains stage(t+1); safe, compiler-visible
    }
    ALOAD(31);
    COMPUTE(1);

    // ---- epilogue: scale + bias, direct store (identical to verified r3) ----
    const int ncol = n0 + (w << 4) + cl;
    const float s  = scales[ncol] * (1.0f / 127.0f);
    const float bv = bias[ncol];
    const int rb = cq << 2;
#pragma unroll
    for (int m = 0; m < 4; ++m) {
#pragma unroll
        for (int r = 0; r < 4; ++r) {
            int mg = (h << 6) + (m << 4) + rb + r;
            out[(size_t)mg * ND + ncol] = acc[m][r] * s + bv;
        }
    }
#undef STAGE
#undef ALOAD
#undef COMPUTE
}

extern "C" void kernel_launch(void* const* d_in, const int* in_sizes, int n_in,
                              void* d_out, int out_size, void* d_ws, size_t ws_size,
                              hipStream_t stream) {
    const float* x      = (const float*)d_in[0];
    const int*   wgt    = (const int*)d_in[1];     // int8 promoted to int32 by harness
    const float* scales = (const float*)d_in[2];
    const float* bias   = (const float*)d_in[3];
    float* out = (float*)d_out;
    ushort* xp = (ushort*)d_ws;                    // 1 MiB bf16 packed x

    pack_x_kernel<<<MD * KD / (8 * 256), 256, 0, stream>>>(x, xp);
    gemm_kernel<<<512, 256, 0, stream>>>(wgt, xp, scales, bias, out);
}

// Round 9
// 71.594 us; speedup vs baseline: 1.3697x; 1.3270x over previous
//
#include <hip/hip_runtime.h>
#include <hip/hip_bf16.h>

typedef __attribute__((ext_vector_type(8))) short short8;   // 8 x bf16 (4 VGPR)
typedef __attribute__((ext_vector_type(4))) float f32x4;
typedef __attribute__((ext_vector_type(4))) int   i32x4;

#define KD 4096
#define ND 16384
#define MD 128

// round-to-nearest-even f32 -> bf16 bits
__device__ __forceinline__ ushort f2bf_rn(float f) {
    unsigned u = __float_as_uint(f);
    u += 0x7FFFu + ((u >> 16) & 1u);
    return (ushort)(u >> 16);
}

// exact for |v| <= 127: int -> f32 -> truncate to bf16 (small ints have zero low mantissa bits)
__device__ __forceinline__ ushort i2bf(int v) {
    return (ushort)(__float_as_uint((float)v) >> 16);
}

// Pack x[128][4096] f32 into bf16 MFMA A-fragment order (verified r1/r3):
// xp[kb][mt][lane][j] = x[16*mt + (lane&15)][32*kb + 8*(lane>>4) + j]   (1 MiB)
__global__ __launch_bounds__(256) void pack_x_kernel(const float* __restrict__ x,
                                                     ushort* __restrict__ xp) {
    int tid  = blockIdx.x * 256 + threadIdx.x;   // 0..65535
    int lane = tid & 63;
    int mt   = (tid >> 6) & 7;
    int kb   = tid >> 9;                          // 0..127
    int m = (mt << 4) + (lane & 15);
    int k = (kb << 5) + ((lane >> 4) << 3);
    const f32x4* src = reinterpret_cast<const f32x4*>(x + (size_t)m * KD + k);
    f32x4 a = src[0];
    f32x4 b = src[1];
    short8 v;
    v[0] = (short)f2bf_rn(a[0]); v[1] = (short)f2bf_rn(a[1]);
    v[2] = (short)f2bf_rn(a[2]); v[3] = (short)f2bf_rn(a[3]);
    v[4] = (short)f2bf_rn(b[0]); v[5] = (short)f2bf_rn(b[1]);
    v[6] = (short)f2bf_rn(b[2]); v[7] = (short)f2bf_rn(b[3]);
    *reinterpret_cast<short8*>(xp + (size_t)tid * 8) = v;
}

#define GLOAD_LDS16(g, l)                                                        \
    __builtin_amdgcn_global_load_lds((const __attribute__((address_space(1))) void*)(g), \
                                     (__attribute__((address_space(3))) void*)(l), 16, 0, 0)

// Block: 32 output cols x ALL 128 output rows x full K=4096. 256 threads (4 waves):
// wave w -> (m-half mh = w>>1, col-group cg = w&1). W is staged ONCE per block and
// consumed by both m-halves -> W dedup is intra-block & deterministic (r3 relied on
// cross-block L2 hit timing). Grid 512 -> 2 blocks/CU. LDS: A dbuf 2x16K [0,32K),
// W dbuf 2x8K [32K,48K) = 48 KiB. Phase template byte-identical to verified r3:
// STAGE(t+1); COMPUTE(t); __syncthreads().
__global__ __launch_bounds__(256, 2) void gemm_kernel(const int* __restrict__ wgt,
                                                      const ushort* __restrict__ xp,
                                                      const float* __restrict__ scales,
                                                      const float* __restrict__ bias,
                                                      float* __restrict__ out) {
    __shared__ __align__(16) char lds[49152];

    const int tid  = threadIdx.x;
    const int lane = tid & 63;
    const int w    = tid >> 6;          // wave 0..3
    const int cg   = w & 1;             // col-group: cols [16cg, 16cg+16)
    const int mh   = w >> 1;            // m-half: rows [64mh, 64mh+64)
    const int nb   = blockIdx.x;        // 0..511, n0 = nb*32
    const int n0   = nb << 5;
    const int cl   = lane & 15;
    const int cq   = lane >> 4;         // k-quarter 0..3

    // ---- A staging: pure linear copy of xp chunk t (16 KiB), 4 issues/wave ----
    // segment s = w*4+i ; src = xp + t*16384 + s*1024 + lane*16 ; dest = A[b] + s*1024
    const char* asrc = (const char*)xp + (w << 12) + (lane << 4);

    // ---- W staging: 8 KiB (32 cols x 256 B), 2 issues/wave ----
    // segment j = w*2+i covers cols 4j..4j+3: lane l -> c = 4j + (l>>4),
    // k = 4*(l&15) ^ ((c&7)<<2)  => LDS layout off(c,k) = c*256 + ((4k)^((c&7)<<4))
    const int* wsrcA;
    const int* wsrcB;
    {
        int j0 = w << 1;
        int c0 = (j0 << 2) + cq;
        int c1 = ((j0 + 1) << 2) + cq;
        wsrcA = wgt + (size_t)(n0 + c0) * KD + ((cl << 2) ^ ((c0 & 7) << 2));
        wsrcB = wgt + (size_t)(n0 + c1) * KD + ((cl << 2) ^ ((c1 & 7) << 2));
    }

    f32x4 acc[4];
#pragma unroll
    for (int i = 0; i < 4; ++i) acc[i] = (f32x4){0.f, 0.f, 0.f, 0.f};

    // LDS dest bases (wave-uniform; HW adds lane*16)
    char* dA = lds + (w << 12);                 // + b*16384 + i*1024
    char* dW = lds + 32768 + (w << 11);         // + b*8192  + i*1024

#define STAGE(t, b) do {                                                        \
        const char* _as = asrc + (size_t)(t) * 16384;                           \
        char* _dA = dA + (b) * 16384;                                           \
        GLOAD_LDS16(_as,        _dA);                                           \
        GLOAD_LDS16(_as + 1024, _dA + 1024);                                    \
        GLOAD_LDS16(_as + 2048, _dA + 2048);                                    \
        GLOAD_LDS16(_as + 3072, _dA + 3072);                                    \
        const int _k0 = (t) * 64;                                               \
        char* _dW = dW + (b) * 8192;                                            \
        GLOAD_LDS16(wsrcA + _k0, _dW);                                          \
        GLOAD_LDS16(wsrcB + _k0, _dW + 1024);                                   \
    } while (0)

    // compute-side read bases (r3's verified patterns)
    const char* rA = lds + (mh << 12) + (lane << 4);        // + b*16384 + kbl*8192 + m*1024
    const char* rW = lds + 32768 + (((cg << 4) + cl) << 8); // + b*8192 + inner
    const unsigned sw  = (unsigned)((cl & 7) << 4);
    const unsigned q32 = (unsigned)(cq << 5);

#define COMPUTE(b) do {                                                         \
        _Pragma("unroll")                                                       \
        for (int _kbl = 0; _kbl < 2; ++_kbl) {                                  \
            unsigned _ib = (unsigned)((_kbl << 7) + q32) ^ sw;                  \
            i32x4 _lo = *reinterpret_cast<const i32x4*>(rW + (b) * 8192 + _ib);         \
            i32x4 _hi = *reinterpret_cast<const i32x4*>(rW + (b) * 8192 + (_ib ^ 16u)); \
            short8 _bf;                                                         \
            _bf[0] = (short)i2bf(_lo[0]); _bf[1] = (short)i2bf(_lo[1]);         \
            _bf[2] = (short)i2bf(_lo[2]); _bf[3] = (short)i2bf(_lo[3]);         \
            _bf[4] = (short)i2bf(_hi[0]); _bf[5] = (short)i2bf(_hi[1]);         \
            _bf[6] = (short)i2bf(_hi[2]); _bf[7] = (short)i2bf(_hi[3]);         \
            const char* _ab = rA + (b) * 16384 + _kbl * 8192;                   \
            _Pragma("unroll")                                                   \
            for (int _m = 0; _m < 4; ++_m) {                                    \
                short8 _af = *reinterpret_cast<const short8*>(_ab + _m * 1024); \
                acc[_m] = __builtin_amdgcn_mfma_f32_16x16x32_bf16(_af, _bf, acc[_m], 0, 0, 0); \
            }                                                                   \
        }                                                                       \
    } while (0)

    // ---- main loop: 64 chunks of K=64, verified 2-phase template ----
    STAGE(0, 0);
    __syncthreads();
#pragma unroll 1
    for (int t = 0; t < 63; ++t) {
        const int cb = t & 1;
        STAGE(t + 1, cb ^ 1);
        COMPUTE(cb);
        __syncthreads();
    }
    COMPUTE(1);

    // ---- epilogue: scale + bias, direct store (block owns its 32x128 tile) ----
    const int ncol = n0 + (cg << 4) + cl;
    const float s  = scales[ncol] * (1.0f / 127.0f);
    const float bv = bias[ncol];
    const int rb = cq << 2;
#pragma unroll
    for (int m = 0; m < 4; ++m) {
#pragma unroll
        for (int r = 0; r < 4; ++r) {
            int mg = (mh << 6) + (m << 4) + rb + r;
            out[(size_t)mg * ND + ncol] = acc[m][r] * s + bv;
        }
    }
#undef STAGE
#undef COMPUTE
}

extern "C" void kernel_launch(void* const* d_in, const int* in_sizes, int n_in,
                              void* d_out, int out_size, void* d_ws, size_t ws_size,
                              hipStream_t stream) {
    const float* x      = (const float*)d_in[0];
    const int*   wgt    = (const int*)d_in[1];     // int8 promoted to int32 by harness
    const float* scales = (const float*)d_in[2];
    const float* bias   = (const float*)d_in[3];
    float* out = (float*)d_out;
    ushort* xp = (ushort*)d_ws;                    // 1 MiB bf16 packed x

    pack_x_kernel<<<MD * KD / (8 * 256), 256, 0, stream>>>(x, xp);
    gemm_kernel<<<512, 256, 0, stream>>>(wgt, xp, scales, bias, out);
}

// Round 10
// 57.404 us; speedup vs baseline: 1.7083x; 1.2472x over previous
//
#include <hip/hip_runtime.h>
#include <hip/hip_bf16.h>

typedef __attribute__((ext_vector_type(8))) short short8;   // 8 x bf16 (4 VGPR)
typedef __attribute__((ext_vector_type(4))) float f32x4;
typedef __attribute__((ext_vector_type(4))) int   i32x4;

#define KD 4096
#define ND 16384
#define MD 128

// round-to-nearest-even f32 -> bf16 bits
__device__ __forceinline__ ushort f2bf_rn(float f) {
    unsigned u = __float_as_uint(f);
    u += 0x7FFFu + ((u >> 16) & 1u);
    return (ushort)(u >> 16);
}

// exact for |v| <= 127: int -> f32 -> truncate to bf16 (small ints have zero low mantissa bits)
__device__ __forceinline__ ushort i2bf(int v) {
    return (ushort)(__float_as_uint((float)v) >> 16);
}

// Pack x[128][4096] f32 into bf16 MFMA A-fragment order (verified r1/r3):
// xp[kb][mt][lane][j] = x[16*mt + (lane&15)][32*kb + 8*(lane>>4) + j]   (1 MiB)
__global__ __launch_bounds__(256) void pack_x_kernel(const float* __restrict__ x,
                                                     ushort* __restrict__ xp) {
    int tid  = blockIdx.x * 256 + threadIdx.x;   // 0..65535
    int lane = tid & 63;
    int mt   = (tid >> 6) & 7;
    int kb   = tid >> 9;                          // 0..127
    int m = (mt << 4) + (lane & 15);
    int k = (kb << 5) + ((lane >> 4) << 3);
    const f32x4* src = reinterpret_cast<const f32x4*>(x + (size_t)m * KD + k);
    f32x4 a = src[0];
    f32x4 b = src[1];
    short8 v;
    v[0] = (short)f2bf_rn(a[0]); v[1] = (short)f2bf_rn(a[1]);
    v[2] = (short)f2bf_rn(a[2]); v[3] = (short)f2bf_rn(a[3]);
    v[4] = (short)f2bf_rn(b[0]); v[5] = (short)f2bf_rn(b[1]);
    v[6] = (short)f2bf_rn(b[2]); v[7] = (short)f2bf_rn(b[3]);
    *reinterpret_cast<short8*>(xp + (size_t)tid * 8) = v;
}

#define GLOAD_LDS16(g, l)                                                        \
    __builtin_amdgcn_global_load_lds((const __attribute__((address_space(1))) void*)(g), \
                                     (__attribute__((address_space(3))) void*)(l), 16, 0, 0)

// Producer/consumer wave specialization. Block = 512 threads (8 waves), grid 256
// (1 block/CU). Tile: 64 cols x ALL 128 rows x full K. W fetched exactly once
// globally (intra-block reuse across all 8 m-tiles).
//   waves 0..3  CONSUMERS: compute 16 cols each, acc[8]; plain __syncthreads()
//               (their vmcnt queue is EMPTY -> the implicit vmcnt(0) is free, and
//               the legalizer inserts no vmcnt before their ds_reads).
//   waves 4..7  PRODUCERS: issue 8 global_load_lds per stage, 2 stages ahead,
//               raw s_barrier + counted vmcnt(8) (no ds_reads in these waves ->
//               nothing for the legalizer to poison).
// LDS: A 3x16K [0,48K) + W 3x16K [48K,96K), stage s -> buffer s%3.
__global__ __launch_bounds__(512) void gemm_kernel(const int* __restrict__ wgt,
                                                   const ushort* __restrict__ xp,
                                                   const float* __restrict__ scales,
                                                   const float* __restrict__ bias,
                                                   float* __restrict__ out) {
    __shared__ __align__(16) char lds[98304];

    const int tid  = threadIdx.x;
    const int lane = tid & 63;
    const int w    = tid >> 6;          // wave 0..7
    const int n0   = blockIdx.x << 6;   // 256 blocks x 64 cols
    const int cl   = lane & 15;
    const int cq   = lane >> 4;         // 0..3

    if (w >= 4) {
        // ================= PRODUCER =================
        const int p = w - 4;            // 0..3
        // A: segments s = p*4+i (16 x 1 KiB = full 16 KiB chunk), linear copy
        const char* asrc = (const char*)xp + (p << 12) + (lane << 4);
        // W: cols c = 16p + 4i + cq, pre-swizzled source (verified r3 layout:
        // off(c,k) = c*256 + ((4k) ^ ((c&7)<<4)))
        const int* wsrc0;
        const int* wsrc1;
        const int* wsrc2;
        const int* wsrc3;
        {
            int c0 = (p << 4) + 0  + cq;
            int c1 = (p << 4) + 4  + cq;
            int c2 = (p << 4) + 8  + cq;
            int c3 = (p << 4) + 12 + cq;
            wsrc0 = wgt + (size_t)(n0 + c0) * KD + ((cl ^ (c0 & 7)) << 2);
            wsrc1 = wgt + (size_t)(n0 + c1) * KD + ((cl ^ (c1 & 7)) << 2);
            wsrc2 = wgt + (size_t)(n0 + c2) * KD + ((cl ^ (c2 & 7)) << 2);
            wsrc3 = wgt + (size_t)(n0 + c3) * KD + ((cl ^ (c3 & 7)) << 2);
        }
        char* dA = lds + (p << 12);             // + b*16384 + i*1024
        char* dW = lds + 49152 + (p << 12);     // + b*16384 + i*1024

#define STAGE(t, b) do {                                                        \
            const char* _as = asrc + (size_t)(t) * 16384;                       \
            char* _dA = dA + (b) * 16384;                                       \
            GLOAD_LDS16(_as,        _dA);                                       \
            GLOAD_LDS16(_as + 1024, _dA + 1024);                                \
            GLOAD_LDS16(_as + 2048, _dA + 2048);                                \
            GLOAD_LDS16(_as + 3072, _dA + 3072);                                \
            const int _k0 = (t) * 64;                                           \
            char* _dW = dW + (b) * 16384;                                       \
            GLOAD_LDS16(wsrc0 + _k0, _dW);                                      \
            GLOAD_LDS16(wsrc1 + _k0, _dW + 1024);                               \
            GLOAD_LDS16(wsrc2 + _k0, _dW + 2048);                               \
            GLOAD_LDS16(wsrc3 + _k0, _dW + 3072);                               \
        } while (0)

        STAGE(0, 0);
        STAGE(1, 1);
        asm volatile("s_waitcnt vmcnt(8)" ::: "memory");   // stage 0 landed
        __builtin_amdgcn_s_barrier();                       // entry barrier

        int b2 = 2;                      // buffer of stage t+2
#pragma unroll 1
        for (int t = 0; t < 64; ++t) {
            if (t + 2 < 64) {
                STAGE(t + 2, b2);
                asm volatile("s_waitcnt vmcnt(8)" ::: "memory");  // stage t+1 landed
            } else if (t + 1 < 64) {
                asm volatile("s_waitcnt vmcnt(0)" ::: "memory");  // stage 63 landed
            }
            __builtin_amdgcn_s_barrier();
            b2 = (b2 == 2) ? 0 : b2 + 1;
        }
#undef STAGE
        return;   // producers write no output
    }

    // ================= CONSUMER (waves 0..3) =================
    f32x4 acc[8];
#pragma unroll
    for (int i = 0; i < 8; ++i) acc[i] = (f32x4){0.f, 0.f, 0.f, 0.f};

    // read bases (r3's verified patterns)
    const char* rA = lds + (lane << 4);                     // + b*16384 + j*8192 + mt*1024
    const char* rW = lds + 49152 + (((w << 4) + cl) << 8);  // + b*16384 + inner
    const unsigned sw  = (unsigned)((cl & 7) << 4);
    const unsigned q32 = (unsigned)(cq << 5);

    __syncthreads();                                        // entry barrier (vmcnt empty)

    int bc = 0;
#pragma unroll 1
    for (int t = 0; t < 64; ++t) {
        const char* wb = rW + bc * 16384;
        const char* ab = rA + bc * 16384;
#pragma unroll
        for (int j = 0; j < 2; ++j) {
            unsigned off = (unsigned)((j << 7) + q32) ^ sw;
            i32x4 lo = *reinterpret_cast<const i32x4*>(wb + off);
            i32x4 hi = *reinterpret_cast<const i32x4*>(wb + (off ^ 16u));
            short8 bf;
            bf[0] = (short)i2bf(lo[0]); bf[1] = (short)i2bf(lo[1]);
            bf[2] = (short)i2bf(lo[2]); bf[3] = (short)i2bf(lo[3]);
            bf[4] = (short)i2bf(hi[0]); bf[5] = (short)i2bf(hi[1]);
            bf[6] = (short)i2bf(hi[2]); bf[7] = (short)i2bf(hi[3]);
            const char* aj = ab + j * 8192;
#pragma unroll
            for (int mt = 0; mt < 8; ++mt) {
                short8 af = *reinterpret_cast<const short8*>(aj + mt * 1024);
                acc[mt] = __builtin_amdgcn_mfma_f32_16x16x32_bf16(af, bf, acc[mt], 0, 0, 0);
            }
        }
        __syncthreads();
        bc = (bc == 2) ? 0 : bc + 1;
    }

    // ---- epilogue: scale + bias, direct store (block owns 128 x 64 tile) ----
    const int ncol = n0 + (w << 4) + cl;
    const float s  = scales[ncol] * (1.0f / 127.0f);
    const float bv = bias[ncol];
    const int rb = cq << 2;
#pragma unroll
    for (int mt = 0; mt < 8; ++mt) {
#pragma unroll
        for (int r = 0; r < 4; ++r) {
            int mg = (mt << 4) + rb + r;
            out[(size_t)mg * ND + ncol] = acc[mt][r] * s + bv;
        }
    }
}

extern "C" void kernel_launch(void* const* d_in, const int* in_sizes, int n_in,
                              void* d_out, int out_size, void* d_ws, size_t ws_size,
                              hipStream_t stream) {
    const float* x      = (const float*)d_in[0];
    const int*   wgt    = (const int*)d_in[1];     // int8 promoted to int32 by harness
    const float* scales = (const float*)d_in[2];
    const float* bias   = (const float*)d_in[3];
    float* out = (float*)d_out;
    ushort* xp = (ushort*)d_ws;                    // 1 MiB bf16 packed x

    pack_x_kernel<<<MD * KD / (8 * 256), 256, 0, stream>>>(x, xp);
    gemm_kernel<<<256, 512, 0, stream>>>(wgt, xp, scales, bias, out);
}